// Round 4
// baseline (3833.595 us; speedup 1.0000x reference)
//
#include <hip/hip_runtime.h>
#include <hip/hip_bf16.h>
#include <math.h>

#define STEPS 2048
#define BATCH 512

typedef __attribute__((ext_vector_type(8))) short short8;
typedef __attribute__((ext_vector_type(4))) short short4v;
typedef __attribute__((ext_vector_type(2))) short short2v;
typedef __attribute__((ext_vector_type(4))) float f32x4;
typedef __attribute__((ext_vector_type(2))) float f32x2;

__device__ __forceinline__ short f2bf(float f) {
    union { float f; unsigned u; } v; v.f = f;
    unsigned u = v.u;
    return (short)((u + 0x7FFFu + ((u >> 16) & 1u)) >> 16);  // RNE
}
__device__ __forceinline__ short2v pk2(float a, float b) {
    __hip_bfloat162 h = __float22bfloat162_rn(make_float2(a, b));
    union { __hip_bfloat162 h; short2v s; } u; u.h = h; return u.s;
}

// Light barrier: LDS-visibility only (lgkm), no vmcnt drain — global prefetch
// loads and the out-store stay in flight across it.
#define LBAR() do { asm volatile("s_waitcnt lgkmcnt(0)" ::: "memory"); \
                    __builtin_amdgcn_s_barrier();                      \
                    asm volatile("" ::: "memory"); } while (0)

// ---------------------------------------------------------------------------
// baseflow[b] = 25th percentile (linear interp) of flow[:, b]
// ---------------------------------------------------------------------------
__global__ __launch_bounds__(256) void baseflow_kernel(
    const float* __restrict__ hyd, float* __restrict__ bf)
{
    __shared__ float arr[STEPS];
    const int b = blockIdx.x;
    const int tid = threadIdx.x;
    for (int t = tid; t < STEPS; t += 256)
        arr[t] = hyd[(size_t)(t * BATCH + b) * 17];
    __syncthreads();
    for (int k = 2; k <= STEPS; k <<= 1) {
        for (int j = k >> 1; j > 0; j >>= 1) {
            for (int i = tid; i < STEPS; i += 256) {
                int ixj = i ^ j;
                if (ixj > i) {
                    float a = arr[i], c = arr[ixj];
                    bool up = ((i & k) == 0);
                    if (up ? (a > c) : (a < c)) { arr[i] = c; arr[ixj] = a; }
                }
            }
            __syncthreads();
        }
    }
    if (tid == 0) bf[b] = arr[511] + 0.75f * (arr[512] - arr[511]);
}

// ---------------------------------------------------------------------------
// R4: 512 blocks x 256 threads (4 waves), ONE batch column per block.
// Rationale: step time is ~64% unhideable dependency latency (LDS roundtrips,
// MFMA/exp chains, serial exchange loop) with only 1 wave/SIMD resident.
// 1 col/block doubles blocks -> 2 blocks/CU -> 2 independent chains per SIMD;
// block B's issue fills block A's stalls (blocks never barrier together).
// Per-block issue is ~unchanged: column 2 previously rode free in MFMA
// B-operand lanes, and the tail was already redundant across lanes.
// NOTE: rain = hyd[...,1] (x[:,:,0]); hyd[...,0] is flow.
// ---------------------------------------------------------------------------
__global__ __launch_bounds__(256, 1) void hyd_step_kernel(
    const float* __restrict__ hyd,
    const float* __restrict__ W0,  const float* __restrict__ b0,
    const float* __restrict__ W1,  const float* __restrict__ b1,
    const float* __restrict__ Win, const float* __restrict__ bin,
    const float* __restrict__ Wout,const float* __restrict__ bout,
    const float* __restrict__ baseflow,
    float* __restrict__ out)
{
    __shared__ __align__(16) short h1F[256 * 8];
    __shared__ __align__(16) short h2F[256 * 8];
    __shared__ __align__(16) float hb[100];      // heads out (single column)

    const int tid  = threadIdx.x;
    const int blk  = blockIdx.x;                 // == batch column
    const int lane = tid & 63;
    const int wv   = tid >> 6;
    const int cn   = lane & 15;
    const int cg   = lane >> 4;

    for (int i = tid; i < 256 * 8; i += 256) { h1F[i] = 0; h2F[i] = 0; }

    // ---- weight A-fragments + bias C-inits (one-time) ----
    short8 a0[2]; f32x4 c0[2];
    short8 a1[2][4]; f32x4 c1[2];
    short8 ah[2][4]; f32x4 ch[2];
    #pragma unroll
    for (int i = 0; i < 2; ++i) {
        const int mt = 2 * wv + i;
        const int row = mt * 16 + cn;
        #pragma unroll
        for (int j = 0; j < 8; ++j) {
            int k = cg * 8 + j;
            a0[i][j] = (k < 24) ? f2bf(W0[row * 24 + k]) : (short)0;
        }
        #pragma unroll
        for (int kt = 0; kt < 4; ++kt)
            #pragma unroll
            for (int j = 0; j < 8; ++j)
                a1[i][kt][j] = f2bf(W1[row * 128 + kt * 32 + cg * 8 + j]);
        #pragma unroll
        for (int r = 0; r < 4; ++r) {
            int m = mt * 16 + cg * 4 + r;
            c0[i][r] = b0[m];
            c1[i][r] = b1[m];
        }
    }
    const int nht = (wv < 2) ? 2 : 1;
    int htile[2];
    htile[0] = (wv < 2) ? 2 * wv : 4 + (wv - 2);
    htile[1] = (wv < 2) ? 2 * wv + 1 : htile[0];
    // head row remap: LDS position p -> source row q:
    //   p==0 -> q=0 ; p==1 -> dummy zero ; p>=2 -> q=p-1 (valid while q<89)
    #pragma unroll
    for (int i = 0; i < 2; ++i) {
        const int ht = htile[i];
        const int row = ht * 16 + cn;     // p
        #pragma unroll
        for (int kt = 0; kt < 4; ++kt)
            #pragma unroll
            for (int j = 0; j < 8; ++j) {
                int k = kt * 32 + cg * 8 + j;
                float w = 0.f;
                if (row != 1) {
                    int q = (row == 0) ? 0 : (row - 1);
                    if (q < 9)       w = Win[q * 128 + k];
                    else if (q < 89) w = Wout[(q - 9) * 128 + k];
                }
                ah[i][kt][j] = f2bf(w);
            }
        #pragma unroll
        for (int r = 0; r < 4; ++r) {
            int m = ht * 16 + cg * 4 + r;  // p
            float bb = 0.f;
            if (m != 1) {
                int q = (m == 0) ? 0 : (m - 1);
                if (q < 9)       bb = bin[q];
                else if (q < 89) bb = bout[q - 9];
            }
            ch[i][r] = bb;
        }
    }

    // ---- recurrent state (float2 pairs), replicated on every lane ----
    f32x2 s01 = {0.f, 1.f}, s23 = {0.f, 0.f}, s45 = {0.f, 0.f}, s67 = {0.f, 0.f};
    const float bfv = baseflow[blk];
    short8 spack;
    {
        short2v p0 = pk2(0.01f * s01.x, 0.01f * s01.y);
        short2v p1 = pk2(0.01f * s23.x, 0.01f * s23.y);
        short2v p2 = pk2(0.01f * s45.x, 0.01f * s45.y);
        short2v p3 = pk2(0.01f * s67.x, 0.01f * s67.y);
        spack[0] = p0[0]; spack[1] = p0[1]; spack[2] = p1[0]; spack[3] = p1[1];
        spack[4] = p2[0]; spack[5] = p2[1]; spack[6] = p3[0]; spack[7] = p3[1];
    }

    // ---- x/rain register prefetch state (single column blk) ----
    const bool xlane = (cn == 0) && (cg < 2);
    const int xoff = blk * 17 + 1 + cg * 8;      // floats 1+cg*8.. of row
    const int roff = blk * 17 + 1;               // rain = hyd[...,1]
    float xv[8];
    float rain_next;
    if (xlane) {
        const float* p = hyd + xoff;
        #pragma unroll
        for (int j = 0; j < 8; ++j) xv[j] = p[j];
    }
    rain_next = hyd[roff];

    // acc_x(0) = W0x @ x(0) + b0  (x part of L0, K slots 0..15; cg>=2 zero)
    f32x4 accx0, accx1;
    {
        short8 xfrag = 0;
        if (xlane) {
            short2v q0 = pk2(xv[0], xv[1]), q1 = pk2(xv[2], xv[3]),
                    q2 = pk2(xv[4], xv[5]), q3 = pk2(xv[6], xv[7]);
            xfrag[0] = q0[0]; xfrag[1] = q0[1]; xfrag[2] = q1[0]; xfrag[3] = q1[1];
            xfrag[4] = q2[0]; xfrag[5] = q2[1]; xfrag[6] = q3[0]; xfrag[7] = q3[1];
        }
        accx0 = __builtin_amdgcn_mfma_f32_16x16x32_bf16(a0[0], xfrag, c0[0], 0, 0, 0);
        accx1 = __builtin_amdgcn_mfma_f32_16x16x32_bf16(a0[1], xfrag, c0[1], 0, 0, 0);
    }

    for (int t = 0; t < STEPS; ++t) {
        const float rain = rain_next;
        // issue prefetch for t+1 (stays in flight across LBARs)
        const int tn = (t + 1 < STEPS) ? (t + 1) : t;
        const float* px = hyd + (size_t)tn * (BATCH * 17);
        if (xlane) {
            const float* p = px + xoff;
            #pragma unroll
            for (int j = 0; j < 8; ++j) xv[j] = p[j];
        }
        rain_next = px[roff];

        // === L0 stores-part: h1 = relu(acc_x + W0s @ (0.01*stores)) ===
        short8 sfrag = 0;
        if (cn == 0 && cg == 2) sfrag = spack;    // K slots 16..23
        #pragma unroll
        for (int i = 0; i < 2; ++i) {
            f32x4 acc = __builtin_amdgcn_mfma_f32_16x16x32_bf16(
                a0[i], sfrag, (i ? accx1 : accx0), 0, 0, 0);
            if (cn == 0) {
                int m0 = (2 * wv + i) * 16 + cg * 4;
                short4v p;
                short2v pa = pk2(fmaxf(acc[0], 0.f), fmaxf(acc[1], 0.f));
                short2v pb = pk2(fmaxf(acc[2], 0.f), fmaxf(acc[3], 0.f));
                p[0] = pa[0]; p[1] = pa[1]; p[2] = pb[0]; p[3] = pb[1];
                *(short4v*)&h1F[((m0 >> 3) * 16 + cn) * 8 + (m0 & 7)] = p;
            }
        }
        LBAR();   // B1 (lgkm only)

        // === L1: h2 = relu(W1 @ h1 + b1), 2x2-deep MFMA chains ===
        short8 bf1[4];
        #pragma unroll
        for (int kt = 0; kt < 4; ++kt)
            bf1[kt] = *(const short8*)&h1F[(kt * 64 + lane) * 8];
        #pragma unroll
        for (int i = 0; i < 2; ++i) {
            f32x4 zz = {0.f, 0.f, 0.f, 0.f};
            f32x4 accA = __builtin_amdgcn_mfma_f32_16x16x32_bf16(a1[i][0], bf1[0], c1[i], 0, 0, 0);
            accA = __builtin_amdgcn_mfma_f32_16x16x32_bf16(a1[i][1], bf1[1], accA, 0, 0, 0);
            f32x4 accB = __builtin_amdgcn_mfma_f32_16x16x32_bf16(a1[i][2], bf1[2], zz, 0, 0, 0);
            accB = __builtin_amdgcn_mfma_f32_16x16x32_bf16(a1[i][3], bf1[3], accB, 0, 0, 0);
            f32x4 acc = accA + accB;
            if (cn == 0) {
                int m0 = (2 * wv + i) * 16 + cg * 4;
                short4v p;
                short2v pa = pk2(fmaxf(acc[0], 0.f), fmaxf(acc[1], 0.f));
                short2v pb = pk2(fmaxf(acc[2], 0.f), fmaxf(acc[3], 0.f));
                p[0] = pa[0]; p[1] = pa[1]; p[2] = pb[0]; p[3] = pb[1];
                *(short4v*)&h2F[((m0 >> 3) * 16 + cn) * 8 + (m0 & 7)] = p;
            }
        }
        LBAR();   // B2

        // === heads: exp(logits) p<10 (p=1 dummy), sigmoid(gates) p>=10 ===
        short8 bf2[4];
        #pragma unroll
        for (int kt = 0; kt < 4; ++kt)
            bf2[kt] = *(const short8*)&h2F[(kt * 64 + lane) * 8];
        #pragma unroll
        for (int i = 0; i < 2; ++i) {
            if (i < nht) {
                f32x4 zz = {0.f, 0.f, 0.f, 0.f};
                f32x4 accA = __builtin_amdgcn_mfma_f32_16x16x32_bf16(ah[i][0], bf2[0], ch[i], 0, 0, 0);
                accA = __builtin_amdgcn_mfma_f32_16x16x32_bf16(ah[i][1], bf2[1], accA, 0, 0, 0);
                f32x4 accB = __builtin_amdgcn_mfma_f32_16x16x32_bf16(ah[i][2], bf2[2], zz, 0, 0, 0);
                accB = __builtin_amdgcn_mfma_f32_16x16x32_bf16(ah[i][3], bf2[3], accB, 0, 0, 0);
                f32x4 acc = accA + accB;
                if (cn == 0) {
                    const int ht = htile[i];
                    f32x4 o;
                    if (ht == 0) {        // mixed exp/sigmoid (runtime cg)
                        #pragma unroll
                        for (int r = 0; r < 4; ++r) {
                            int m = cg * 4 + r;
                            float v = acc[r];
                            bool isl = (m < 10);
                            float em = __expf(isl ? v : -v);
                            o[r] = isl ? em : __builtin_amdgcn_rcpf(1.f + em);
                        }
                    } else {              // pure sigmoid
                        #pragma unroll
                        for (int r = 0; r < 4; ++r) {
                            float em = __expf(-acc[r]);
                            o[r] = __builtin_amdgcn_rcpf(1.f + em);
                        }
                    }
                    *(f32x4*)&hb[ht * 16 + cg * 4] = o;
                }
            }
        }
        LBAR();   // B3

        // === gather half A (floats 0..43) + shadow acc_x(t+1) ===
        f32x4 gqA[11];
        #pragma unroll
        for (int c2 = 0; c2 < 11; ++c2)
            gqA[c2] = *(const f32x4*)&hb[c2 * 4];
        {
            short8 xfrag = 0;
            if (xlane) {
                short2v q0 = pk2(xv[0], xv[1]), q1 = pk2(xv[2], xv[3]),
                        q2 = pk2(xv[4], xv[5]), q3 = pk2(xv[6], xv[7]);
                xfrag[0] = q0[0]; xfrag[1] = q0[1]; xfrag[2] = q1[0]; xfrag[3] = q1[1];
                xfrag[4] = q2[0]; xfrag[5] = q2[1]; xfrag[6] = q3[0]; xfrag[7] = q3[1];
            }
            accx0 = __builtin_amdgcn_mfma_f32_16x16x32_bf16(a0[0], xfrag, c0[0], 0, 0, 0);
            accx1 = __builtin_amdgcn_mfma_f32_16x16x32_bf16(a0[1], xfrag, c0[1], 0, 0, 0);
        }

        // === tail part 1: softmax + exchange d=0..3 (uses only half A) ===
        const float* gvA = (const float*)gqA;
        const f32x2* gA2 = (const f32x2*)gqA;
        {
            f32x2 dt = (gA2[1] + gA2[2]) + (gA2[3] + gA2[4]);
            float den = gvA[0] + dt.x + dt.y;
            float rr = rain * __builtin_amdgcn_rcpf(den);
            f32x2 rr2 = {rr, rr};
            s01 += gA2[1] * rr2; s23 += gA2[2] * rr2;
            s45 += gA2[3] * rr2; s67 += gA2[4] * rr2;

            #pragma unroll
            for (int d = 0; d < 4; ++d) {
                const int gb = 5 + 4 * d;
                f32x2 fb0 = gA2[gb + 0] * s01, fb1 = gA2[gb + 1] * s23;
                f32x2 fb2 = gA2[gb + 2] * s45, fb3 = gA2[gb + 3] * s67;
                f32x2 tt = (fb0 + fb1) + (fb2 + fb3);
                float fs = tt.x + tt.y;
                s01 -= fb0; s23 -= fb1; s45 -= fb2; s67 -= fb3;
                if      (d == 0) s01.x += fs;
                else if (d == 1) s01.y += fs;
                else if (d == 2) s23.x += fs;
                else             s23.y += fs;
            }
        }

        // === gather half B (floats 40..91) + tail part 2 ===
        f32x4 gqB[13];
        #pragma unroll
        for (int c2 = 0; c2 < 13; ++c2)
            gqB[c2] = *(const f32x4*)&hb[40 + c2 * 4];
        const float* gvB = (const float*)gqB;
        const f32x2* gB2 = (const f32x2*)gqB;
        {
            #pragma unroll
            for (int d = 4; d < 8; ++d) {
                const int gb = 4 * d - 15;   // pair index into B (floats-40)/2
                f32x2 fb0 = gB2[gb + 0] * s01, fb1 = gB2[gb + 1] * s23;
                f32x2 fb2 = gB2[gb + 2] * s45, fb3 = gB2[gb + 3] * s67;
                f32x2 tt = (fb0 + fb1) + (fb2 + fb3);
                float fs = tt.x + tt.y;
                s01 -= fb0; s23 -= fb1; s45 -= fb2; s67 -= fb3;
                if      (d == 4) s45.x += fs;
                else if (d == 5) s45.y += fs;
                else if (d == 6) s67.x += fs;
                else             s67.y += fs;
            }
            // escape: floats 74..81 -> B pairs 17..20
            s01 -= gB2[17] * s01; s23 -= gB2[18] * s23;
            s45 -= gB2[19] * s45; s67 -= gB2[20] * s67;
            // flow: floats 82..89 -> B pairs 21..24
            f32x2 f0 = gB2[21] * s01, f1 = gB2[22] * s23;
            f32x2 f2 = gB2[23] * s45, f3 = gB2[24] * s67;
            f32x2 ft = (f0 + f1) + (f2 + f3);
            float fsum = ft.x + ft.y;
            s01 -= f0; s23 -= f1; s45 -= f2; s67 -= f3;
            if (t == 0) s23.x = bfv / fmaxf(gvB[44], 1e-5f);  // b_flow[SLOW], p=84

            {
                short2v p0 = pk2(0.01f * s01.x, 0.01f * s01.y);
                short2v p1 = pk2(0.01f * s23.x, 0.01f * s23.y);
                short2v p2 = pk2(0.01f * s45.x, 0.01f * s45.y);
                short2v p3 = pk2(0.01f * s67.x, 0.01f * s67.y);
                spack[0] = p0[0]; spack[1] = p0[1]; spack[2] = p1[0]; spack[3] = p1[1];
                spack[4] = p2[0]; spack[5] = p2[1]; spack[6] = p3[0]; spack[7] = p3[1];
            }
            if (tid == 0) out[(size_t)t * BATCH + blk] = fsum;
        }
        // no B4: stores live in registers; h1F(t+1) writes are ordered
        // after every wave's h1F(t) reads by B2(t)/B3(t).
    }
}

// ---------------------------------------------------------------------------
extern "C" void kernel_launch(void* const* d_in, const int* in_sizes, int n_in,
                              void* d_out, int out_size, void* d_ws, size_t ws_size,
                              hipStream_t stream)
{
    const float* hyd  = (const float*)d_in[0];
    const float* W0   = (const float*)d_in[1];
    const float* b0   = (const float*)d_in[2];
    const float* W1   = (const float*)d_in[3];
    const float* b1   = (const float*)d_in[4];
    const float* Win  = (const float*)d_in[5];
    const float* bin  = (const float*)d_in[6];
    const float* Wout = (const float*)d_in[7];
    const float* bout = (const float*)d_in[8];
    float* out = (float*)d_out;
    float* bf  = (float*)d_ws;

    baseflow_kernel<<<BATCH, 256, 0, stream>>>(hyd, bf);
    hyd_step_kernel<<<BATCH, 256, 0, stream>>>(
        hyd, W0, b0, W1, b1, Win, bin, Wout, bout, bf, out);
}

// Round 6
// 2916.583 us; speedup vs baseline: 1.3144x; 1.3144x over previous
//
#include <hip/hip_runtime.h>
#include <hip/hip_bf16.h>
#include <math.h>

#define STEPS 2048
#define BATCH 512

typedef __attribute__((ext_vector_type(8))) short short8;
typedef __attribute__((ext_vector_type(4))) short short4v;
typedef __attribute__((ext_vector_type(2))) short short2v;
typedef __attribute__((ext_vector_type(4))) float f32x4;
typedef __attribute__((ext_vector_type(2))) float f32x2;

__device__ __forceinline__ short f2bf(float f) {
    union { float f; unsigned u; } v; v.f = f;
    unsigned u = v.u;
    return (short)((u + 0x7FFFu + ((u >> 16) & 1u)) >> 16);  // RNE
}
__device__ __forceinline__ short2v pk2(float a, float b) {
    __hip_bfloat162 h = __float22bfloat162_rn(make_float2(a, b));
    union { __hip_bfloat162 h; short2v s; } u; u.h = h; return u.s;
}

// Light barrier: LDS-visibility only (lgkm), no vmcnt drain — global prefetch
// loads and the out-store stay in flight across it.
#define LBAR() do { asm volatile("s_waitcnt lgkmcnt(0)" ::: "memory"); \
                    __builtin_amdgcn_s_barrier();                      \
                    asm volatile("" ::: "memory"); } while (0)

// ---------------------------------------------------------------------------
// baseflow[b] = 25th percentile (linear interp) of flow[:, b]
// ---------------------------------------------------------------------------
__global__ __launch_bounds__(256) void baseflow_kernel(
    const float* __restrict__ hyd, float* __restrict__ bf)
{
    __shared__ float arr[STEPS];
    const int b = blockIdx.x;
    const int tid = threadIdx.x;
    for (int t = tid; t < STEPS; t += 256)
        arr[t] = hyd[(size_t)(t * BATCH + b) * 17];
    __syncthreads();
    for (int k = 2; k <= STEPS; k <<= 1) {
        for (int j = k >> 1; j > 0; j >>= 1) {
            for (int i = tid; i < STEPS; i += 256) {
                int ixj = i ^ j;
                if (ixj > i) {
                    float a = arr[i], c = arr[ixj];
                    bool up = ((i & k) == 0);
                    if (up ? (a > c) : (a < c)) { arr[i] = c; arr[ixj] = a; }
                }
            }
            __syncthreads();
        }
    }
    if (tid == 0) bf[b] = arr[511] + 0.75f * (arr[512] - arr[511]);
}

// ---------------------------------------------------------------------------
// R5 (resubmit; prior round was an infra failure): R3 structure (2 cols/block,
// 256 blocks, 4 waves, 3 LBARs) — R4 proved extra chains per CU land ~1:1 on
// the critical chain (shared VALU issue + per-CU LDS pipe). Deltas vs R3:
//  - 0.01 stores-scale folded into W0's stores-columns at init: the tail's
//    spack now packs raw stores (4 pk_mul removed from the chain's end).
//  - head tiles rebalanced wv0:{0} wv1:{1,2} wv2:{3,4} wv3:{5}: the exp-heavy
//    mixed tile no longer rides the max-work wave, shortening B3 arrival.
// NOTE: rain = hyd[...,1] (x[:,:,0]); hyd[...,0] is flow.
// ---------------------------------------------------------------------------
__global__ __launch_bounds__(256, 1) void hyd_step_kernel(
    const float* __restrict__ hyd,
    const float* __restrict__ W0,  const float* __restrict__ b0,
    const float* __restrict__ W1,  const float* __restrict__ b1,
    const float* __restrict__ Win, const float* __restrict__ bin,
    const float* __restrict__ Wout,const float* __restrict__ bout,
    const float* __restrict__ baseflow,
    float* __restrict__ out)
{
    __shared__ __align__(16) short h1F[256 * 8];
    __shared__ __align__(16) short h2F[256 * 8];
    __shared__ __align__(16) float hb[2][100];   // stride 100: bank-conflict-free

    const int tid  = threadIdx.x;
    const int blk  = blockIdx.x;
    const int lane = tid & 63;
    const int wv   = tid >> 6;
    const int cn   = lane & 15;
    const int cg   = lane >> 4;
    const int col  = lane & 1;    // tail column owned by this lane

    for (int i = tid; i < 256 * 8; i += 256) { h1F[i] = 0; h2F[i] = 0; }

    // ---- weight A-fragments + bias C-inits (one-time) ----
    short8 a0[2]; f32x4 c0[2];
    short8 a1[2][4]; f32x4 c1[2];
    short8 ah[2][4]; f32x4 ch[2];
    #pragma unroll
    for (int i = 0; i < 2; ++i) {
        const int mt = 2 * wv + i;
        const int row = mt * 16 + cn;
        #pragma unroll
        for (int j = 0; j < 8; ++j) {
            int k = cg * 8 + j;
            // stores-columns (k>=16) pre-scaled by 0.01: spack packs raw s
            float w = 0.f;
            if (k < 16)      w = W0[row * 24 + k];
            else if (k < 24) w = 0.01f * W0[row * 24 + k];
            a0[i][j] = f2bf(w);
        }
        #pragma unroll
        for (int kt = 0; kt < 4; ++kt)
            #pragma unroll
            for (int j = 0; j < 8; ++j)
                a1[i][kt][j] = f2bf(W1[row * 128 + kt * 32 + cg * 8 + j]);
        #pragma unroll
        for (int r = 0; r < 4; ++r) {
            int m = mt * 16 + cg * 4 + r;
            c0[i][r] = b0[m];
            c1[i][r] = b1[m];
        }
    }
    // head tile assignment: wv0:{0} (exp-mixed), wv1:{1,2}, wv2:{3,4}, wv3:{5}
    const int nht = (wv == 1 || wv == 2) ? 2 : 1;
    int htile[2];
    htile[0] = (wv == 0) ? 0 : (wv == 1) ? 1 : (wv == 2) ? 3 : 5;
    htile[1] = htile[0] + ((nht == 2) ? 1 : 0);
    // head row remap: LDS position p -> source row q:
    //   p==0 -> q=0 ; p==1 -> dummy zero ; p>=2 -> q=p-1 (valid while q<89)
    #pragma unroll
    for (int i = 0; i < 2; ++i) {
        const int ht = htile[i];
        const int row = ht * 16 + cn;     // p
        #pragma unroll
        for (int kt = 0; kt < 4; ++kt)
            #pragma unroll
            for (int j = 0; j < 8; ++j) {
                int k = kt * 32 + cg * 8 + j;
                float w = 0.f;
                if (row != 1) {
                    int q = (row == 0) ? 0 : (row - 1);
                    if (q < 9)       w = Win[q * 128 + k];
                    else if (q < 89) w = Wout[(q - 9) * 128 + k];
                }
                ah[i][kt][j] = f2bf(w);
            }
        #pragma unroll
        for (int r = 0; r < 4; ++r) {
            int m = ht * 16 + cg * 4 + r;  // p
            float bb = 0.f;
            if (m != 1) {
                int q = (m == 0) ? 0 : (m - 1);
                if (q < 9)       bb = bin[q];
                else if (q < 89) bb = bout[q - 9];
            }
            ch[i][r] = bb;
        }
    }

    // ---- recurrent state (float2 pairs), replicated per lane for column col ----
    f32x2 s01 = {0.f, 1.f}, s23 = {0.f, 0.f}, s45 = {0.f, 0.f}, s67 = {0.f, 0.f};
    const float bfv = baseflow[blk * 2 + col];
    short8 spack;
    {
        short2v p0 = pk2(s01.x, s01.y);
        short2v p1 = pk2(s23.x, s23.y);
        short2v p2 = pk2(s45.x, s45.y);
        short2v p3 = pk2(s67.x, s67.y);
        spack[0] = p0[0]; spack[1] = p0[1]; spack[2] = p1[0]; spack[3] = p1[1];
        spack[4] = p2[0]; spack[5] = p2[1]; spack[6] = p3[0]; spack[7] = p3[1];
    }

    // ---- x/rain register prefetch state ----
    const bool xlane = (cn < 2) && (cg < 2);
    const int xoff = (blk * 2 + cn) * 17 + 1 + cg * 8;   // floats 1+cg*8 .. of row
    const int roff = (blk * 2 + col) * 17 + 1;           // rain = hyd[...,1]
    float xv[8];
    float rain_next;
    if (xlane) {
        const float* p = hyd + xoff;
        #pragma unroll
        for (int j = 0; j < 8; ++j) xv[j] = p[j];
    }
    rain_next = hyd[roff];

    // acc_x(0) = W0x @ x(0) + b0  (x part of L0, K slots 0..15; cg>=2 zero)
    f32x4 accx0, accx1;
    {
        short8 xfrag = 0;
        if (xlane) {
            short2v q0 = pk2(xv[0], xv[1]), q1 = pk2(xv[2], xv[3]),
                    q2 = pk2(xv[4], xv[5]), q3 = pk2(xv[6], xv[7]);
            xfrag[0] = q0[0]; xfrag[1] = q0[1]; xfrag[2] = q1[0]; xfrag[3] = q1[1];
            xfrag[4] = q2[0]; xfrag[5] = q2[1]; xfrag[6] = q3[0]; xfrag[7] = q3[1];
        }
        accx0 = __builtin_amdgcn_mfma_f32_16x16x32_bf16(a0[0], xfrag, c0[0], 0, 0, 0);
        accx1 = __builtin_amdgcn_mfma_f32_16x16x32_bf16(a0[1], xfrag, c0[1], 0, 0, 0);
    }

    for (int t = 0; t < STEPS; ++t) {
        const float rain = rain_next;
        // issue prefetch for t+1 (consumed post-B3; stays in flight across
        // LBARs — never drained, so HBM latency is fully hidden)
        const int tn = (t + 1 < STEPS) ? (t + 1) : t;
        const float* px = hyd + (size_t)tn * (BATCH * 17);
        if (xlane) {
            const float* p = px + xoff;
            #pragma unroll
            for (int j = 0; j < 8; ++j) xv[j] = p[j];
        }
        rain_next = px[roff];

        // === L0 stores-part: h1 = relu(acc_x + W0s' @ stores) ===
        short8 sfrag = 0;
        if (cn < 2 && cg == 2) sfrag = spack;     // K slots 16..23
        #pragma unroll
        for (int i = 0; i < 2; ++i) {
            f32x4 acc = __builtin_amdgcn_mfma_f32_16x16x32_bf16(
                a0[i], sfrag, (i ? accx1 : accx0), 0, 0, 0);
            if (cn < 2) {
                int m0 = (2 * wv + i) * 16 + cg * 4;
                short4v p;
                short2v pa = pk2(fmaxf(acc[0], 0.f), fmaxf(acc[1], 0.f));
                short2v pb = pk2(fmaxf(acc[2], 0.f), fmaxf(acc[3], 0.f));
                p[0] = pa[0]; p[1] = pa[1]; p[2] = pb[0]; p[3] = pb[1];
                *(short4v*)&h1F[((m0 >> 3) * 16 + cn) * 8 + (m0 & 7)] = p;
            }
        }
        LBAR();   // B1 (lgkm only)

        // === L1: h2 = relu(W1 @ h1 + b1), 2x2-deep MFMA chains ===
        short8 bf1[4];
        #pragma unroll
        for (int kt = 0; kt < 4; ++kt)
            bf1[kt] = *(const short8*)&h1F[(kt * 64 + lane) * 8];
        #pragma unroll
        for (int i = 0; i < 2; ++i) {
            f32x4 zz = {0.f, 0.f, 0.f, 0.f};
            f32x4 accA = __builtin_amdgcn_mfma_f32_16x16x32_bf16(a1[i][0], bf1[0], c1[i], 0, 0, 0);
            accA = __builtin_amdgcn_mfma_f32_16x16x32_bf16(a1[i][1], bf1[1], accA, 0, 0, 0);
            f32x4 accB = __builtin_amdgcn_mfma_f32_16x16x32_bf16(a1[i][2], bf1[2], zz, 0, 0, 0);
            accB = __builtin_amdgcn_mfma_f32_16x16x32_bf16(a1[i][3], bf1[3], accB, 0, 0, 0);
            f32x4 acc = accA + accB;
            if (cn < 2) {
                int m0 = (2 * wv + i) * 16 + cg * 4;
                short4v p;
                short2v pa = pk2(fmaxf(acc[0], 0.f), fmaxf(acc[1], 0.f));
                short2v pb = pk2(fmaxf(acc[2], 0.f), fmaxf(acc[3], 0.f));
                p[0] = pa[0]; p[1] = pa[1]; p[2] = pb[0]; p[3] = pb[1];
                *(short4v*)&h2F[((m0 >> 3) * 16 + cn) * 8 + (m0 & 7)] = p;
            }
        }
        LBAR();   // B2

        // === heads: exp(logits) p<10 (p=1 dummy), sigmoid(gates) p>=10 ===
        short8 bf2[4];
        #pragma unroll
        for (int kt = 0; kt < 4; ++kt)
            bf2[kt] = *(const short8*)&h2F[(kt * 64 + lane) * 8];
        #pragma unroll
        for (int i = 0; i < 2; ++i) {
            if (i < nht) {
                f32x4 zz = {0.f, 0.f, 0.f, 0.f};
                f32x4 accA = __builtin_amdgcn_mfma_f32_16x16x32_bf16(ah[i][0], bf2[0], ch[i], 0, 0, 0);
                accA = __builtin_amdgcn_mfma_f32_16x16x32_bf16(ah[i][1], bf2[1], accA, 0, 0, 0);
                f32x4 accB = __builtin_amdgcn_mfma_f32_16x16x32_bf16(ah[i][2], bf2[2], zz, 0, 0, 0);
                accB = __builtin_amdgcn_mfma_f32_16x16x32_bf16(ah[i][3], bf2[3], accB, 0, 0, 0);
                f32x4 acc = accA + accB;
                if (cn < 2) {
                    const int ht = htile[i];
                    f32x4 o;
                    if (ht == 0) {        // mixed exp/sigmoid (runtime cg)
                        #pragma unroll
                        for (int r = 0; r < 4; ++r) {
                            int m = cg * 4 + r;
                            float v = acc[r];
                            bool isl = (m < 10);
                            float em = __expf(isl ? v : -v);
                            o[r] = isl ? em : __builtin_amdgcn_rcpf(1.f + em);
                        }
                    } else {              // pure sigmoid
                        #pragma unroll
                        for (int r = 0; r < 4; ++r) {
                            float em = __expf(-acc[r]);
                            o[r] = __builtin_amdgcn_rcpf(1.f + em);
                        }
                    }
                    *(f32x4*)&hb[cn][ht * 16 + cg * 4] = o;
                }
            }
        }
        LBAR();   // B3

        // === gather half A (floats 0..43) + shadow acc_x(t+1) ===
        f32x4 gqA[11];
        #pragma unroll
        for (int c2 = 0; c2 < 11; ++c2)
            gqA[c2] = *(const f32x4*)&hb[col][c2 * 4];
        {
            short8 xfrag = 0;
            if (xlane) {
                short2v q0 = pk2(xv[0], xv[1]), q1 = pk2(xv[2], xv[3]),
                        q2 = pk2(xv[4], xv[5]), q3 = pk2(xv[6], xv[7]);
                xfrag[0] = q0[0]; xfrag[1] = q0[1]; xfrag[2] = q1[0]; xfrag[3] = q1[1];
                xfrag[4] = q2[0]; xfrag[5] = q2[1]; xfrag[6] = q3[0]; xfrag[7] = q3[1];
            }
            accx0 = __builtin_amdgcn_mfma_f32_16x16x32_bf16(a0[0], xfrag, c0[0], 0, 0, 0);
            accx1 = __builtin_amdgcn_mfma_f32_16x16x32_bf16(a0[1], xfrag, c0[1], 0, 0, 0);
        }

        // === tail part 1: softmax + exchange d=0..3 (uses only half A) ===
        const float* gvA = (const float*)gqA;
        const f32x2* gA2 = (const f32x2*)gqA;
        {
            f32x2 dt = (gA2[1] + gA2[2]) + (gA2[3] + gA2[4]);
            float den = gvA[0] + dt.x + dt.y;
            float rr = rain * __builtin_amdgcn_rcpf(den);
            f32x2 rr2 = {rr, rr};
            s01 += gA2[1] * rr2; s23 += gA2[2] * rr2;
            s45 += gA2[3] * rr2; s67 += gA2[4] * rr2;

            #pragma unroll
            for (int d = 0; d < 4; ++d) {
                const int gb = 5 + 4 * d;
                f32x2 fb0 = gA2[gb + 0] * s01, fb1 = gA2[gb + 1] * s23;
                f32x2 fb2 = gA2[gb + 2] * s45, fb3 = gA2[gb + 3] * s67;
                f32x2 tt = (fb0 + fb1) + (fb2 + fb3);
                float fs = tt.x + tt.y;
                s01 -= fb0; s23 -= fb1; s45 -= fb2; s67 -= fb3;
                if      (d == 0) s01.x += fs;
                else if (d == 1) s01.y += fs;
                else if (d == 2) s23.x += fs;
                else             s23.y += fs;
            }
        }

        // === gather half B (floats 40..91) + tail part 2 ===
        f32x4 gqB[13];
        #pragma unroll
        for (int c2 = 0; c2 < 13; ++c2)
            gqB[c2] = *(const f32x4*)&hb[col][40 + c2 * 4];
        const float* gvB = (const float*)gqB;
        const f32x2* gB2 = (const f32x2*)gqB;
        {
            #pragma unroll
            for (int d = 4; d < 8; ++d) {
                const int gb = 4 * d - 15;   // pair index into B (floats-40)/2
                f32x2 fb0 = gB2[gb + 0] * s01, fb1 = gB2[gb + 1] * s23;
                f32x2 fb2 = gB2[gb + 2] * s45, fb3 = gB2[gb + 3] * s67;
                f32x2 tt = (fb0 + fb1) + (fb2 + fb3);
                float fs = tt.x + tt.y;
                s01 -= fb0; s23 -= fb1; s45 -= fb2; s67 -= fb3;
                if      (d == 4) s45.x += fs;
                else if (d == 5) s45.y += fs;
                else if (d == 6) s67.x += fs;
                else             s67.y += fs;
            }
            // escape: floats 74..81 -> B pairs 17..20
            s01 -= gB2[17] * s01; s23 -= gB2[18] * s23;
            s45 -= gB2[19] * s45; s67 -= gB2[20] * s67;
            // flow: floats 82..89 -> B pairs 21..24
            f32x2 f0 = gB2[21] * s01, f1 = gB2[22] * s23;
            f32x2 f2 = gB2[23] * s45, f3 = gB2[24] * s67;
            f32x2 ft = (f0 + f1) + (f2 + f3);
            float fsum = ft.x + ft.y;
            s01 -= f0; s23 -= f1; s45 -= f2; s67 -= f3;
            if (t == 0) s23.x = bfv / fmaxf(gvB[44], 1e-5f);  // b_flow[SLOW], p=84

            {
                short2v p0 = pk2(s01.x, s01.y);
                short2v p1 = pk2(s23.x, s23.y);
                short2v p2 = pk2(s45.x, s45.y);
                short2v p3 = pk2(s67.x, s67.y);
                spack[0] = p0[0]; spack[1] = p0[1]; spack[2] = p1[0]; spack[3] = p1[1];
                spack[4] = p2[0]; spack[5] = p2[1]; spack[6] = p3[0]; spack[7] = p3[1];
            }
            if (tid < 2) out[(size_t)t * BATCH + blk * 2 + tid] = fsum;
        }
        // no B4: stores live in registers; h1F(t+1) writes are ordered
        // after every wave's h1F(t) reads by B2(t)/B3(t); hb(t) reads complete
        // before B1(t+1), hb(t+1) writes happen after B2(t+1).
    }
}

// ---------------------------------------------------------------------------
extern "C" void kernel_launch(void* const* d_in, const int* in_sizes, int n_in,
                              void* d_out, int out_size, void* d_ws, size_t ws_size,
                              hipStream_t stream)
{
    const float* hyd  = (const float*)d_in[0];
    const float* W0   = (const float*)d_in[1];
    const float* b0   = (const float*)d_in[2];
    const float* W1   = (const float*)d_in[3];
    const float* b1   = (const float*)d_in[4];
    const float* Win  = (const float*)d_in[5];
    const float* bin  = (const float*)d_in[6];
    const float* Wout = (const float*)d_in[7];
    const float* bout = (const float*)d_in[8];
    float* out = (float*)d_out;
    float* bf  = (float*)d_ws;

    baseflow_kernel<<<BATCH, 256, 0, stream>>>(hyd, bf);
    hyd_step_kernel<<<BATCH / 2, 256, 0, stream>>>(
        hyd, W0, b0, W1, b1, Win, bin, Wout, bout, bf, out);
}